// Round 3
// baseline (1457.256 us; speedup 1.0000x reference)
//
#include <hip/hip_runtime.h>

// ImplicitResampleModule on MI355X (gfx950). Round: all-swapped-MFMA pipeline.
// - Q/K/V GEMMs ALL operand-swapped (W as A-frag) -> Q, K rows, V rows, and
//   softmax for pixel p=c15 are all in the SAME lane. Logits = in-lane FMAs +
//   shfl_xor over qd; PV = 64 in-lane FMAs. NO LDS use after staging.
// - One barrier total. LDS = 40960 B exactly -> 4 blocks/CU (16 waves/CU).
// - No unbarriered LDS write->read (R2's NaN: TBAA no-alias reorder on the
//   vT scratch). All LDS RAW pairs cross the single __syncthreads().
// - k-sliced XOR-keyed LDS layouts: ~2-way max conflict on frag reads.
// - Plain (not nontemporal) stores: restore L2 write-combining.
//
// d_ws layout (use_t: ws >= 68,552,192 B):
//   [0, 64MB)            featT  u16 [B][HW][C]
//   [64MB, +1MB)         offsC  f32 [B*THW*2]
//   [+1MB, +128K ...)    WqC, WkC, WvC  u16[65536] each
//   [+1MB+384K, ...)     bqC, bkC, bvC  u16[256] each (512 B apart)

using short8 = __attribute__((ext_vector_type(8))) short;   // 8 bf16
using uint4v = __attribute__((ext_vector_type(4))) unsigned;
using f32x4  = __attribute__((ext_vector_type(4))) float;
typedef unsigned short u16;

#define LOG2_1E4 13.287712379549449f
#define TWO_PI   6.283185307179586f
#define ATT_SCL  0.17677669529663687f   // 32^-0.5

__device__ __forceinline__ float bs2f(u16 s) {
    unsigned u = ((unsigned)s) << 16;
    float f; __builtin_memcpy(&f, &u, 4); return f;
}
__device__ __forceinline__ u16 f2bs(float f) {
    unsigned u; __builtin_memcpy(&u, &f, 4);
    u += 0x7fffu + ((u >> 16) & 1u);   // RNE
    return (u16)(u >> 16);
}
// HW packed f32->bf16 (RNE): dst.lo = bf16(lo), dst.hi = bf16(hi)
__device__ __forceinline__ unsigned cvt_pk_bf16(float lo, float hi) {
    unsigned r;
    asm("v_cvt_pk_bf16_f32 %0, %1, %2" : "=v"(r) : "v"(lo), "v"(hi));
    return r;
}

// Probe: bf16-decode offs at even u16 indices. Block-uniform result.
__device__ __forceinline__ int probe_is_f32(const u16* offs_raw) {
    const int lane = threadIdx.x & 63;
    const float v = bs2f(offs_raw[lane * 2]);
    const float av = fabsf(v);
    const bool insane = !(av >= 1e-3f && av <= 1000.0f);   // NaN -> insane
    return __popcll(__ballot(insane)) >= 16 ? 1 : 0;
}

// ---------------- canonicalize offs / weights / biases ----------------
__global__ __launch_bounds__(256) void irm_canon(
    const void* offs_raw, const void* Wq_r, const void* bq_r,
    const void* Wk_r, const void* bk_r, const void* Wv_r, const void* bv_r,
    unsigned char* canon)
{
    const int is_f32 = probe_is_f32((const u16*)offs_raw);
    float* offsC = (float*)canon;
    u16* WqC = (u16*)(canon + (1u << 20));
    u16* WkC = (u16*)(canon + (1u << 20) + (1u << 17));
    u16* WvC = (u16*)(canon + (1u << 20) + (2u << 17));
    u16* bqC = (u16*)(canon + (1u << 20) + (3u << 17));
    u16* bkC = bqC + 256;
    u16* bvC = bkC + 256;

    const int gid = blockIdx.x * 256 + threadIdx.x;
    if (gid < 262144) {
        offsC[gid] = is_f32 ? ((const float*)offs_raw)[gid]
                            : bs2f(((const u16*)offs_raw)[gid]);
    } else if (gid < 262144 + 3 * 65536) {
        const int r = gid - 262144, w = r >> 16, i = r & 65535;
        const void* src = (w == 0) ? Wq_r : (w == 1) ? Wk_r : Wv_r;
        u16*       dst  = (w == 0) ? WqC  : (w == 1) ? WkC  : WvC;
        dst[i] = is_f32 ? f2bs(((const float*)src)[i]) : ((const u16*)src)[i];
    } else if (gid < 262144 + 3 * 65536 + 3 * 256) {
        const int r = gid - 262144 - 3 * 65536, w = r >> 8, i = r & 255;
        const void* src = (w == 0) ? bq_r : (w == 1) ? bk_r : bv_r;
        u16*       dst  = (w == 0) ? bqC  : (w == 1) ? bkC  : bvC;
        dst[i] = is_f32 ? f2bs(((const float*)src)[i]) : ((const u16*)src)[i];
    }
}

// ---------------- transpose feat [B,C,HW] -> featT bf16 [B,HW,C] ----------------
__global__ __launch_bounds__(256) void irm_transpose(const void* __restrict__ feat_raw,
                                                     const u16* __restrict__ offs_raw,
                                                     u16* __restrict__ featT) {
    const int is_f32 = probe_is_f32(offs_raw);
    __shared__ u16 tile[64][72];
    const int b   = blockIdx.z;
    const int c0  = blockIdx.y << 6;
    const int hw0 = blockIdx.x << 6;
    const int tid = threadIdx.x;
    const int r    = tid >> 4;          // 0..15
    const int col4 = (tid & 15) << 2;   // 0..60
    #pragma unroll
    for (int it = 0; it < 4; ++it) {
        const int c = (it << 4) + r;
        const size_t idx = ((size_t)((b << 8) + c0 + c) << 16) + hw0 + col4;
        ushort4 o;
        if (is_f32) {
            const float4 v = *(const float4*)((const float*)feat_raw + idx);
            const unsigned lo = cvt_pk_bf16(v.x, v.y);
            const unsigned hi = cvt_pk_bf16(v.z, v.w);
            o.x = (u16)(lo & 0xffffu); o.y = (u16)(lo >> 16);
            o.z = (u16)(hi & 0xffffu); o.w = (u16)(hi >> 16);
        } else {
            o = *(const ushort4*)((const u16*)feat_raw + idx);
        }
        *(ushort4*)&tile[c][col4 ^ (((c >> 3) & 7) << 3)] = o;
    }
    __syncthreads();
    const int s = tid & 7;    // c-octet
    const int m = tid >> 3;   // hw within half-tile
    #pragma unroll
    for (int it2 = 0; it2 < 2; ++it2) {
        const int hw = (it2 << 5) + m;
        short8 o;
        #pragma unroll
        for (int k = 0; k < 8; ++k) {
            const int c = (s << 3) + k;
            o[k] = (short)tile[c][hw ^ (((c >> 3) & 7) << 3)];
        }
        u16* dst = featT + (((size_t)((b << 16) + hw0 + hw)) << 8) + c0 + (s << 3);
        *(short8*)dst = o;
    }
}

// ---------------- main fused kernel ----------------
__global__ __launch_bounds__(256, 4) void irm_main(
    const void* __restrict__ fsrc,   // featT (bf16) if transposed else raw feat
    const int transposed,
    const u16* __restrict__ offs_raw,
    const float* __restrict__ offsC,
    const u16* __restrict__ Wq, const u16* __restrict__ bq,
    const u16* __restrict__ Wk, const u16* __restrict__ bk_unused,
    const u16* __restrict__ Wv, const u16* __restrict__ bv,
    void* __restrict__ out_raw)
{
    const int is_f32 = probe_is_f32(offs_raw);

    // LDS 40960 B -> exactly 4 blocks/CU.
    //  sFb [32 g][16 row][8 u16] @ 0      (8192 B)   row key = (g>>1)&7
    //  sFw [32 g][64 row][8 u16] @ 8192   (32768 B)  row key = (row>>3)&7
    __shared__ __align__(16) unsigned char smem[40960];
    u16* sFb = (u16*)smem;
    u16* sFw = (u16*)(smem + 8192);

    const int tid = threadIdx.x;
    const int raw = blockIdx.x;
    const int wq_ = ((raw & 7) << 10) | (raw >> 3);   // XCD swizzle (8192 % 8 == 0)
    const int b   = wq_ >> 12;
    const int t0  = (wq_ & 4095) << 4;

    const int p0 = tid >> 4;            // pixel 0..15
    const int cx = tid & 15;            // 16-channel group
    const int t  = t0 + p0;
    const float offx = offsC[((((size_t)b << 16) + (size_t)t) << 1) + 0];
    const float offy = offsC[((((size_t)b << 16) + (size_t)t) << 1) + 1];

    // ---- phase 0: gather + inline PE + stage fw, fb (k-sliced layouts) ----
    {
        const int ty = t >> 8, tx = t & 255;
        const float fy = (float)ty + offy;
        const float fx = (float)tx + offx;
        const float fiy = floorf(fy), fix = floorf(fx);
        const int iy = (int)fiy, ix = (int)fix;
        const float dy = fy - fiy, dx = fx - fix;

        int lin4[4];
        #pragma unroll
        for (int u = 0; u < 4; ++u) {
            int hy = iy + (u >> 1); hy = hy < 0 ? 0 : (hy > 255 ? 255 : hy);
            int wx = ix + (u & 1);  wx = wx < 0 ? 0 : (wx > 255 ? 255 : wx);
            lin4[u] = (hy << 8) | wx;
        }

        short8 g[4][2];
        if (transposed) {
            #pragma unroll
            for (int u = 0; u < 4; ++u) {
                const u16* src = (const u16*)fsrc +
                    ((((size_t)(b << 16)) + (size_t)lin4[u]) << 8) + (cx << 4);
                g[u][0] = *(const short8*)(src);
                g[u][1] = *(const short8*)(src + 8);
            }
        } else {
            #pragma unroll
            for (int u = 0; u < 4; ++u) {
                #pragma unroll
                for (int i = 0; i < 8; ++i) {
                    const size_t i0 = (((size_t)((b << 8) + (cx << 4) + i)) << 16) + lin4[u];
                    const size_t i1 = (((size_t)((b << 8) + (cx << 4) + 8 + i)) << 16) + lin4[u];
                    g[u][0][i] = is_f32 ? (short)f2bs(((const float*)fsrc)[i0]) : (short)((const u16*)fsrc)[i0];
                    g[u][1][i] = is_f32 ? (short)f2bs(((const float*)fsrc)[i1]) : (short)((const u16*)fsrc)[i1];
                }
            }
        }

        // inline PE: channel pair a covers c = 16cx + 2a, 2a+1; j = (8cx+a)&63
        float invt[8], s1[8], c1[8];
        #pragma unroll
        for (int a = 0; a < 8; ++a) {
            const int j = ((cx << 3) + a) & 63;
            invt[a] = exp2f(-(float)j * (LOG2_1E4 / 64.0f));
            const float arg = (TWO_PI / (1.0f + 1e-6f)) * invt[a];
            __sincosf(arg, &s1[a], &c1[a]);
        }

        const bool hi_half = (cx >= 8);   // c >= 128 -> x half
        float gsum[16];
        #pragma unroll
        for (int i = 0; i < 16; ++i) gsum[i] = 0.0f;

        #pragma unroll
        for (int u = 0; u < 4; ++u) {
            const bool sel = hi_half ? (bool)(u & 1) : (bool)(u >> 1);
            unsigned pk[8];
            #pragma unroll
            for (int a = 0; a < 8; ++a) {
                const float f0 = bs2f((u16)g[u][a >> 2][(2 * a) & 7]);
                const float f1 = bs2f((u16)g[u][a >> 2][(2 * a + 1) & 7]);
                gsum[2 * a]     += f0;
                gsum[2 * a + 1] += f1;
                const float w0 = f0 + (sel ? s1[a] : 0.0f);
                const float w1 = f1 + (sel ? c1[a] : 1.0f);
                pk[a] = cvt_pk_bf16(w0, w1);
            }
            const int row = (p0 << 2) + u;
            const int rp  = row ^ ((row >> 3) & 7);
            const uint4v lo = {pk[0], pk[1], pk[2], pk[3]};
            const uint4v hi = {pk[4], pk[5], pk[6], pk[7]};
            *(uint4v*)&sFw[(((2 * cx) * 64 + rp)) * 8]     = lo;
            *(uint4v*)&sFw[(((2 * cx + 1) * 64 + rp)) * 8] = hi;
        }

        // fb = mean_u + PE(deci, card = 2)
        const float ys = dy * (TWO_PI / (2.0f + 1e-6f));
        const float xs = dx * (TWO_PI / (2.0f + 1e-6f));
        const float sxy = hi_half ? xs : ys;
        unsigned qk[8];
        #pragma unroll
        for (int a = 0; a < 8; ++a) {
            float s2, c2;
            __sincosf(sxy * invt[a], &s2, &c2);
            qk[a] = cvt_pk_bf16(gsum[2 * a] * 0.25f + s2, gsum[2 * a + 1] * 0.25f + c2);
        }
        const int rb = p0 ^ (cx & 7);
        const uint4v qlo = {qk[0], qk[1], qk[2], qk[3]};
        const uint4v qhi = {qk[4], qk[5], qk[6], qk[7]};
        *(uint4v*)&sFb[((2 * cx) * 16 + rb) * 8]     = qlo;
        *(uint4v*)&sFb[((2 * cx + 1) * 16 + rb) * 8] = qhi;
    }
    __syncthreads();   // the only barrier: all LDS RAW pairs cross it

    const int lane = tid & 63;
    const int wv   = tid >> 6;
    const int c15  = lane & 15;
    const int qd   = lane >> 4;
    const int colbase = wv << 6;
    const f32x4 zero4 = {0.f, 0.f, 0.f, 0.f};
    const int kwkey = (c15 >> 1) & 7;    // = ((4*c15+u)>>3)&7 for u in 0..3
    const int krow0 = 4 * c15;

    // ---- Q^T GEMM (swapped): accQt[nt][r] = Q[p=c15][colbase+16nt+4qd+r] (+bq)
    f32x4 accQt[4];
    #pragma unroll
    for (int nt = 0; nt < 4; ++nt) accQt[nt] = zero4;
    #pragma unroll
    for (int ks = 0; ks < 8; ++ks) {
        const int gidx = ks * 4 + qd;
        const short8 bfb = *(const short8*)&sFb[(gidx * 16 + (c15 ^ ((gidx >> 1) & 7))) * 8];
        #pragma unroll
        for (int nt = 0; nt < 4; ++nt) {
            const short8 aw = *(const short8*)&Wq[(colbase + nt * 16 + c15) * 256 + ks * 32 + qd * 8];
            accQt[nt] = __builtin_amdgcn_mfma_f32_16x16x32_bf16(aw, bfb, accQt[nt], 0, 0, 0);
        }
    }
    #pragma unroll
    for (int nt = 0; nt < 4; ++nt) {
        const ushort4 b4 = *(const ushort4*)&bq[colbase + nt * 16 + qd * 4];
        accQt[nt][0] += bs2f(b4.x); accQt[nt][1] += bs2f(b4.y);
        accQt[nt][2] += bs2f(b4.z); accQt[nt][3] += bs2f(b4.w);
    }

    // ---- K^T GEMM (swapped, per-u): accKt[u][nt][r] = K[4c15+u][colbase+16nt+4qd+r]
    //      (bk is u-independent per (p,h) -> cancels in softmax; dropped)
    f32x4 accKt[4][4];
    #pragma unroll
    for (int u = 0; u < 4; ++u)
        #pragma unroll
        for (int nt = 0; nt < 4; ++nt) accKt[u][nt] = zero4;
    #pragma unroll
    for (int ks = 0; ks < 8; ++ks) {
        short8 aw[4];
        #pragma unroll
        for (int nt = 0; nt < 4; ++nt)
            aw[nt] = *(const short8*)&Wk[(colbase + nt * 16 + c15) * 256 + ks * 32 + qd * 8];
        #pragma unroll
        for (int u = 0; u < 4; ++u) {
            const short8 bf = *(const short8*)&sFw[((ks * 4 + qd) * 64 + ((krow0 + u) ^ kwkey)) * 8];
            #pragma unroll
            for (int nt = 0; nt < 4; ++nt)
                accKt[u][nt] = __builtin_amdgcn_mfma_f32_16x16x32_bf16(aw[nt], bf, accKt[u][nt], 0, 0, 0);
        }
    }

    // ---- logits fully in-lane (pixel p = c15), reduce over qd; exact f32 softmax ----
    float att[4][2];
    {
        float lg[4][2];
        #pragma unroll
        for (int u = 0; u < 4; ++u) {
            #pragma unroll
            for (int h2 = 0; h2 < 2; ++h2) {
                float acc = 0.0f;
                #pragma unroll
                for (int ntl = 0; ntl < 2; ++ntl) {
                    const int nt = h2 * 2 + ntl;
                    #pragma unroll
                    for (int r = 0; r < 4; ++r)
                        acc += accQt[nt][r] * accKt[u][nt][r];
                }
                acc += __shfl_xor(acc, 16);
                acc += __shfl_xor(acc, 32);
                lg[u][h2] = acc * ATT_SCL;
            }
        }
        #pragma unroll
        for (int h2 = 0; h2 < 2; ++h2) {
            const float mx = fmaxf(fmaxf(lg[0][h2], lg[1][h2]), fmaxf(lg[2][h2], lg[3][h2]));
            float e[4], es = 0.0f;
            #pragma unroll
            for (int u = 0; u < 4; ++u) { e[u] = __expf(lg[u][h2] - mx); es += e[u]; }
            const float inv = __fdividef(1.0f, es);
            #pragma unroll
            for (int u = 0; u < 4; ++u) att[u][h2] = e[u] * inv;
        }
    }
    // accQt/accKt dead here -> regs recycle into accVt

    // ---- V^T GEMM (swapped, per-u): accVt[u][nt][r] = V[4c15+u][colbase+16nt+4qd+r]
    f32x4 accVt[4][4];
    #pragma unroll
    for (int u = 0; u < 4; ++u)
        #pragma unroll
        for (int nt = 0; nt < 4; ++nt) accVt[u][nt] = zero4;
    #pragma unroll
    for (int ks = 0; ks < 8; ++ks) {
        short8 aw[4];
        #pragma unroll
        for (int nt = 0; nt < 4; ++nt)
            aw[nt] = *(const short8*)&Wv[(colbase + nt * 16 + c15) * 256 + ks * 32 + qd * 8];
        #pragma unroll
        for (int u = 0; u < 4; ++u) {
            const short8 bf = *(const short8*)&sFw[((ks * 4 + qd) * 64 + ((krow0 + u) ^ kwkey)) * 8];
            #pragma unroll
            for (int nt = 0; nt < 4; ++nt)
                accVt[u][nt] = __builtin_amdgcn_mfma_f32_16x16x32_bf16(aw[nt], bf, accVt[u][nt], 0, 0, 0);
        }
    }

    // ---- PV fully in-lane + store: out[p=c15][n] = sum_u att[u]*V[4p+u][n] + bv[n]
    #pragma unroll
    for (int nt = 0; nt < 4; ++nt) {
        const int h2 = nt >> 1;
        const ushort4 bv4 = *(const ushort4*)&bv[colbase + nt * 16 + qd * 4];
        const float bvf[4] = {bs2f(bv4.x), bs2f(bv4.y), bs2f(bv4.z), bs2f(bv4.w)};
        const int cbase = (b << 8) + colbase + nt * 16 + qd * 4;
        #pragma unroll
        for (int r = 0; r < 4; ++r) {
            float val = att[0][h2] * accVt[0][nt][r];
            val += att[1][h2] * accVt[1][nt][r];
            val += att[2][h2] * accVt[2][nt][r];
            val += att[3][h2] * accVt[3][nt][r];
            val += bvf[r];
            if (is_f32) {
                ((float*)out_raw)[(((size_t)(cbase + r)) << 16) + t0 + c15] = val;
            } else {
                ((u16*)out_raw)[(((size_t)(cbase + r)) << 16) + t0 + c15] = f2bs(val);
            }
        }
    }
}

extern "C" void kernel_launch(void* const* d_in, const int* in_sizes, int n_in,
                              void* d_out, int out_size, void* d_ws, size_t ws_size,
                              hipStream_t stream) {
    const size_t FEATT_BYTES = (size_t)1 << 26;   // 64 MB bf16 featT
    const size_t CANON_BYTES = (1u << 20) + (3u << 17) + 3 * 512;
    const int use_t = (ws_size >= FEATT_BYTES + CANON_BYTES) ? 1 : 0;   // ws_size constant -> capture-safe

    unsigned char* ws    = (unsigned char*)d_ws;
    unsigned char* canon = ws + (use_t ? FEATT_BYTES : 0);
    float* offsC = (float*)canon;
    u16* WqC = (u16*)(canon + (1u << 20));
    u16* WkC = (u16*)(canon + (1u << 20) + (1u << 17));
    u16* WvC = (u16*)(canon + (1u << 20) + (2u << 17));
    u16* bqC = (u16*)(canon + (1u << 20) + (3u << 17));
    u16* bkC = bqC + 256;
    u16* bvC = bkC + 256;

    irm_canon<<<1795, 256, 0, stream>>>(d_in[1], d_in[2], d_in[3], d_in[4],
                                        d_in[5], d_in[6], d_in[7], canon);
    if (use_t)
        irm_transpose<<<dim3(1024, 4, 2), 256, 0, stream>>>(d_in[0], (const u16*)d_in[1], (u16*)ws);
    irm_main<<<dim3(8192), 256, 0, stream>>>(use_t ? (const void*)ws : d_in[0], use_t,
                                             (const u16*)d_in[1], offsC,
                                             WqC, bqC, WkC, bkC, WvC, bvC, d_out);
}

// Round 4
// 843.320 us; speedup vs baseline: 1.7280x; 1.7280x over previous
//
#include <hip/hip_runtime.h>

// ImplicitResampleModule on MI355X (gfx950). Round: R3 structure, spill fix.
// - Q/K/V GEMMs ALL operand-swapped (W as A-frag) -> Q, K rows, V rows, and
//   softmax for pixel p=c15 are all in the SAME lane. Logits = in-lane FMAs +
//   shfl_xor over qd; PV = 64 in-lane FMAs. NO LDS use after staging.
// - One barrier total. LDS = 40960 B.
// - __launch_bounds__(256, 3): R3's (256,4) forced a 128-unified-reg budget
//   -> accumulator spill to scratch (VGPR=64, 5.3 GB HBM traffic, 3x slower).
//   At 3 waves/EU the ~130-reg peak fits; 3 blocks/CU, no scratch.
// - Single accT array reused for K-phase then V-phase (disjoint liveness).
//
// d_ws layout (use_t: ws >= 68,552,192 B):
//   [0, 64MB)            featT  u16 [B][HW][C]
//   [64MB, +1MB)         offsC  f32 [B*THW*2]
//   [+1MB, +128K ...)    WqC, WkC, WvC  u16[65536] each
//   [+1MB+384K, ...)     bqC, bkC, bvC  u16[256] each (512 B apart)

using short8 = __attribute__((ext_vector_type(8))) short;   // 8 bf16
using uint4v = __attribute__((ext_vector_type(4))) unsigned;
using f32x4  = __attribute__((ext_vector_type(4))) float;
typedef unsigned short u16;

#define LOG2_1E4 13.287712379549449f
#define TWO_PI   6.283185307179586f
#define ATT_SCL  0.17677669529663687f   // 32^-0.5

__device__ __forceinline__ float bs2f(u16 s) {
    unsigned u = ((unsigned)s) << 16;
    float f; __builtin_memcpy(&f, &u, 4); return f;
}
__device__ __forceinline__ u16 f2bs(float f) {
    unsigned u; __builtin_memcpy(&u, &f, 4);
    u += 0x7fffu + ((u >> 16) & 1u);   // RNE
    return (u16)(u >> 16);
}
// HW packed f32->bf16 (RNE): dst.lo = bf16(lo), dst.hi = bf16(hi)
__device__ __forceinline__ unsigned cvt_pk_bf16(float lo, float hi) {
    unsigned r;
    asm("v_cvt_pk_bf16_f32 %0, %1, %2" : "=v"(r) : "v"(lo), "v"(hi));
    return r;
}

// Probe: bf16-decode offs at even u16 indices. Block-uniform result.
__device__ __forceinline__ int probe_is_f32(const u16* offs_raw) {
    const int lane = threadIdx.x & 63;
    const float v = bs2f(offs_raw[lane * 2]);
    const float av = fabsf(v);
    const bool insane = !(av >= 1e-3f && av <= 1000.0f);   // NaN -> insane
    return __popcll(__ballot(insane)) >= 16 ? 1 : 0;
}

// ---------------- canonicalize offs / weights / biases ----------------
__global__ __launch_bounds__(256) void irm_canon(
    const void* offs_raw, const void* Wq_r, const void* bq_r,
    const void* Wk_r, const void* bk_r, const void* Wv_r, const void* bv_r,
    unsigned char* canon)
{
    const int is_f32 = probe_is_f32((const u16*)offs_raw);
    float* offsC = (float*)canon;
    u16* WqC = (u16*)(canon + (1u << 20));
    u16* WkC = (u16*)(canon + (1u << 20) + (1u << 17));
    u16* WvC = (u16*)(canon + (1u << 20) + (2u << 17));
    u16* bqC = (u16*)(canon + (1u << 20) + (3u << 17));
    u16* bkC = bqC + 256;
    u16* bvC = bkC + 256;

    const int gid = blockIdx.x * 256 + threadIdx.x;
    if (gid < 262144) {
        offsC[gid] = is_f32 ? ((const float*)offs_raw)[gid]
                            : bs2f(((const u16*)offs_raw)[gid]);
    } else if (gid < 262144 + 3 * 65536) {
        const int r = gid - 262144, w = r >> 16, i = r & 65535;
        const void* src = (w == 0) ? Wq_r : (w == 1) ? Wk_r : Wv_r;
        u16*       dst  = (w == 0) ? WqC  : (w == 1) ? WkC  : WvC;
        dst[i] = is_f32 ? f2bs(((const float*)src)[i]) : ((const u16*)src)[i];
    } else if (gid < 262144 + 3 * 65536 + 3 * 256) {
        const int r = gid - 262144 - 3 * 65536, w = r >> 8, i = r & 255;
        const void* src = (w == 0) ? bq_r : (w == 1) ? bk_r : bv_r;
        u16*       dst  = (w == 0) ? bqC  : (w == 1) ? bkC  : bvC;
        dst[i] = is_f32 ? f2bs(((const float*)src)[i]) : ((const u16*)src)[i];
    }
}

// ---------------- transpose feat [B,C,HW] -> featT bf16 [B,HW,C] ----------------
__global__ __launch_bounds__(256) void irm_transpose(const void* __restrict__ feat_raw,
                                                     const u16* __restrict__ offs_raw,
                                                     u16* __restrict__ featT) {
    const int is_f32 = probe_is_f32(offs_raw);
    __shared__ u16 tile[64][72];
    const int b   = blockIdx.z;
    const int c0  = blockIdx.y << 6;
    const int hw0 = blockIdx.x << 6;
    const int tid = threadIdx.x;
    const int r    = tid >> 4;          // 0..15
    const int col4 = (tid & 15) << 2;   // 0..60
    #pragma unroll
    for (int it = 0; it < 4; ++it) {
        const int c = (it << 4) + r;
        const size_t idx = ((size_t)((b << 8) + c0 + c) << 16) + hw0 + col4;
        ushort4 o;
        if (is_f32) {
            const float4 v = *(const float4*)((const float*)feat_raw + idx);
            const unsigned lo = cvt_pk_bf16(v.x, v.y);
            const unsigned hi = cvt_pk_bf16(v.z, v.w);
            o.x = (u16)(lo & 0xffffu); o.y = (u16)(lo >> 16);
            o.z = (u16)(hi & 0xffffu); o.w = (u16)(hi >> 16);
        } else {
            o = *(const ushort4*)((const u16*)feat_raw + idx);
        }
        *(ushort4*)&tile[c][col4 ^ (((c >> 3) & 7) << 3)] = o;
    }
    __syncthreads();
    const int s = tid & 7;    // c-octet
    const int m = tid >> 3;   // hw within half-tile
    #pragma unroll
    for (int it2 = 0; it2 < 2; ++it2) {
        const int hw = (it2 << 5) + m;
        short8 o;
        #pragma unroll
        for (int k = 0; k < 8; ++k) {
            const int c = (s << 3) + k;
            o[k] = (short)tile[c][hw ^ (((c >> 3) & 7) << 3)];
        }
        u16* dst = featT + (((size_t)((b << 16) + hw0 + hw)) << 8) + c0 + (s << 3);
        *(short8*)dst = o;
    }
}

// ---------------- main fused kernel ----------------
__global__ __launch_bounds__(256, 3) void irm_main(
    const void* __restrict__ fsrc,   // featT (bf16) if transposed else raw feat
    const int transposed,
    const u16* __restrict__ offs_raw,
    const float* __restrict__ offsC,
    const u16* __restrict__ Wq, const u16* __restrict__ bq,
    const u16* __restrict__ Wk, const u16* __restrict__ bk_unused,
    const u16* __restrict__ Wv, const u16* __restrict__ bv,
    void* __restrict__ out_raw)
{
    const int is_f32 = probe_is_f32(offs_raw);

    // LDS 40960 B.
    //  sFb [32 g][16 row][8 u16] @ 0      (8192 B)   row key = (g>>1)&7
    //  sFw [32 g][64 row][8 u16] @ 8192   (32768 B)  row key = (row>>3)&7
    __shared__ __align__(16) unsigned char smem[40960];
    u16* sFb = (u16*)smem;
    u16* sFw = (u16*)(smem + 8192);

    const int tid = threadIdx.x;
    const int raw = blockIdx.x;
    const int wq_ = ((raw & 7) << 10) | (raw >> 3);   // XCD swizzle (8192 % 8 == 0)
    const int b   = wq_ >> 12;
    const int t0  = (wq_ & 4095) << 4;

    const int p0 = tid >> 4;            // pixel 0..15
    const int cx = tid & 15;            // 16-channel group
    const int t  = t0 + p0;
    const float offx = offsC[((((size_t)b << 16) + (size_t)t) << 1) + 0];
    const float offy = offsC[((((size_t)b << 16) + (size_t)t) << 1) + 1];

    // ---- phase 0: gather + inline PE + stage fw, fb (k-sliced layouts) ----
    {
        const int ty = t >> 8, tx = t & 255;
        const float fy = (float)ty + offy;
        const float fx = (float)tx + offx;
        const float fiy = floorf(fy), fix = floorf(fx);
        const int iy = (int)fiy, ix = (int)fix;
        const float dy = fy - fiy, dx = fx - fix;

        int lin4[4];
        #pragma unroll
        for (int u = 0; u < 4; ++u) {
            int hy = iy + (u >> 1); hy = hy < 0 ? 0 : (hy > 255 ? 255 : hy);
            int wx = ix + (u & 1);  wx = wx < 0 ? 0 : (wx > 255 ? 255 : wx);
            lin4[u] = (hy << 8) | wx;
        }

        short8 g[4][2];
        if (transposed) {
            #pragma unroll
            for (int u = 0; u < 4; ++u) {
                const u16* src = (const u16*)fsrc +
                    ((((size_t)(b << 16)) + (size_t)lin4[u]) << 8) + (cx << 4);
                g[u][0] = *(const short8*)(src);
                g[u][1] = *(const short8*)(src + 8);
            }
        } else {
            #pragma unroll
            for (int u = 0; u < 4; ++u) {
                #pragma unroll
                for (int i = 0; i < 8; ++i) {
                    const size_t i0 = (((size_t)((b << 8) + (cx << 4) + i)) << 16) + lin4[u];
                    const size_t i1 = (((size_t)((b << 8) + (cx << 4) + 8 + i)) << 16) + lin4[u];
                    g[u][0][i] = is_f32 ? (short)f2bs(((const float*)fsrc)[i0]) : (short)((const u16*)fsrc)[i0];
                    g[u][1][i] = is_f32 ? (short)f2bs(((const float*)fsrc)[i1]) : (short)((const u16*)fsrc)[i1];
                }
            }
        }

        // inline PE: channel pair a covers c = 16cx + 2a, 2a+1; j = (8cx+a)&63
        float invt[8], s1[8], c1[8];
        #pragma unroll
        for (int a = 0; a < 8; ++a) {
            const int j = ((cx << 3) + a) & 63;
            invt[a] = exp2f(-(float)j * (LOG2_1E4 / 64.0f));
            const float arg = (TWO_PI / (1.0f + 1e-6f)) * invt[a];
            __sincosf(arg, &s1[a], &c1[a]);
        }

        const bool hi_half = (cx >= 8);   // c >= 128 -> x half
        float gsum[16];
        #pragma unroll
        for (int i = 0; i < 16; ++i) gsum[i] = 0.0f;

        #pragma unroll
        for (int u = 0; u < 4; ++u) {
            const bool sel = hi_half ? (bool)(u & 1) : (bool)(u >> 1);
            unsigned pk[8];
            #pragma unroll
            for (int a = 0; a < 8; ++a) {
                const float f0 = bs2f((u16)g[u][a >> 2][(2 * a) & 7]);
                const float f1 = bs2f((u16)g[u][a >> 2][(2 * a + 1) & 7]);
                gsum[2 * a]     += f0;
                gsum[2 * a + 1] += f1;
                const float w0 = f0 + (sel ? s1[a] : 0.0f);
                const float w1 = f1 + (sel ? c1[a] : 1.0f);
                pk[a] = cvt_pk_bf16(w0, w1);
            }
            const int row = (p0 << 2) + u;
            const int rp  = row ^ ((row >> 3) & 7);
            const uint4v lo = {pk[0], pk[1], pk[2], pk[3]};
            const uint4v hi = {pk[4], pk[5], pk[6], pk[7]};
            *(uint4v*)&sFw[(((2 * cx) * 64 + rp)) * 8]     = lo;
            *(uint4v*)&sFw[(((2 * cx + 1) * 64 + rp)) * 8] = hi;
        }

        // fb = mean_u + PE(deci, card = 2)
        const float ys = dy * (TWO_PI / (2.0f + 1e-6f));
        const float xs = dx * (TWO_PI / (2.0f + 1e-6f));
        const float sxy = hi_half ? xs : ys;
        unsigned qk[8];
        #pragma unroll
        for (int a = 0; a < 8; ++a) {
            float s2, c2;
            __sincosf(sxy * invt[a], &s2, &c2);
            qk[a] = cvt_pk_bf16(gsum[2 * a] * 0.25f + s2, gsum[2 * a + 1] * 0.25f + c2);
        }
        const int rb = p0 ^ (cx & 7);
        const uint4v qlo = {qk[0], qk[1], qk[2], qk[3]};
        const uint4v qhi = {qk[4], qk[5], qk[6], qk[7]};
        *(uint4v*)&sFb[((2 * cx) * 16 + rb) * 8]     = qlo;
        *(uint4v*)&sFb[((2 * cx + 1) * 16 + rb) * 8] = qhi;
    }
    __syncthreads();   // the only barrier: all LDS RAW pairs cross it

    const int lane = tid & 63;
    const int wv   = tid >> 6;
    const int c15  = lane & 15;
    const int qd   = lane >> 4;
    const int colbase = wv << 6;
    const f32x4 zero4 = {0.f, 0.f, 0.f, 0.f};
    const int kwkey = (c15 >> 1) & 7;    // = ((4*c15+u)>>3)&7 for u in 0..3
    const int krow0 = 4 * c15;

    // ---- Q^T GEMM (swapped): accQt[nt][r] = Q[p=c15][colbase+16nt+4qd+r] (+bq)
    f32x4 accQt[4];
    #pragma unroll
    for (int nt = 0; nt < 4; ++nt) accQt[nt] = zero4;
    #pragma unroll
    for (int ks = 0; ks < 8; ++ks) {
        const int gidx = ks * 4 + qd;
        const short8 bfb = *(const short8*)&sFb[(gidx * 16 + (c15 ^ ((gidx >> 1) & 7))) * 8];
        #pragma unroll
        for (int nt = 0; nt < 4; ++nt) {
            const short8 aw = *(const short8*)&Wq[(colbase + nt * 16 + c15) * 256 + ks * 32 + qd * 8];
            accQt[nt] = __builtin_amdgcn_mfma_f32_16x16x32_bf16(aw, bfb, accQt[nt], 0, 0, 0);
        }
    }
    #pragma unroll
    for (int nt = 0; nt < 4; ++nt) {
        const ushort4 b4 = *(const ushort4*)&bq[colbase + nt * 16 + qd * 4];
        accQt[nt][0] += bs2f(b4.x); accQt[nt][1] += bs2f(b4.y);
        accQt[nt][2] += bs2f(b4.z); accQt[nt][3] += bs2f(b4.w);
    }

    // ---- K^T GEMM (swapped, per-u) into accT (reused later for V):
    //      accT[u][nt][r] = K[4c15+u][colbase+16nt+4qd+r]
    //      (bk is u-independent per (p,h) -> cancels in softmax; dropped)
    f32x4 accT[4][4];
    #pragma unroll
    for (int u = 0; u < 4; ++u)
        #pragma unroll
        for (int nt = 0; nt < 4; ++nt) accT[u][nt] = zero4;
    #pragma unroll
    for (int ks = 0; ks < 8; ++ks) {
        short8 aw[4];
        #pragma unroll
        for (int nt = 0; nt < 4; ++nt)
            aw[nt] = *(const short8*)&Wk[(colbase + nt * 16 + c15) * 256 + ks * 32 + qd * 8];
        #pragma unroll
        for (int u = 0; u < 4; ++u) {
            const short8 bf = *(const short8*)&sFw[((ks * 4 + qd) * 64 + ((krow0 + u) ^ kwkey)) * 8];
            #pragma unroll
            for (int nt = 0; nt < 4; ++nt)
                accT[u][nt] = __builtin_amdgcn_mfma_f32_16x16x32_bf16(aw[nt], bf, accT[u][nt], 0, 0, 0);
        }
    }

    // ---- logits fully in-lane (pixel p = c15), reduce over qd; exact f32 softmax ----
    float att[4][2];
    {
        float lg[4][2];
        #pragma unroll
        for (int u = 0; u < 4; ++u) {
            #pragma unroll
            for (int h2 = 0; h2 < 2; ++h2) {
                float acc = 0.0f;
                #pragma unroll
                for (int ntl = 0; ntl < 2; ++ntl) {
                    const int nt = h2 * 2 + ntl;
                    #pragma unroll
                    for (int r = 0; r < 4; ++r)
                        acc += accQt[nt][r] * accT[u][nt][r];
                }
                acc += __shfl_xor(acc, 16);
                acc += __shfl_xor(acc, 32);
                lg[u][h2] = acc * ATT_SCL;
            }
        }
        #pragma unroll
        for (int h2 = 0; h2 < 2; ++h2) {
            const float mx = fmaxf(fmaxf(lg[0][h2], lg[1][h2]), fmaxf(lg[2][h2], lg[3][h2]));
            float e[4], es = 0.0f;
            #pragma unroll
            for (int u = 0; u < 4; ++u) { e[u] = __expf(lg[u][h2] - mx); es += e[u]; }
            const float inv = __fdividef(1.0f, es);
            #pragma unroll
            for (int u = 0; u < 4; ++u) att[u][h2] = e[u] * inv;
        }
    }

    // ---- V^T GEMM (swapped, per-u) reusing accT:
    //      accT[u][nt][r] = V[4c15+u][colbase+16nt+4qd+r]
    #pragma unroll
    for (int u = 0; u < 4; ++u)
        #pragma unroll
        for (int nt = 0; nt < 4; ++nt) accT[u][nt] = zero4;
    #pragma unroll
    for (int ks = 0; ks < 8; ++ks) {
        short8 aw[4];
        #pragma unroll
        for (int nt = 0; nt < 4; ++nt)
            aw[nt] = *(const short8*)&Wv[(colbase + nt * 16 + c15) * 256 + ks * 32 + qd * 8];
        #pragma unroll
        for (int u = 0; u < 4; ++u) {
            const short8 bf = *(const short8*)&sFw[((ks * 4 + qd) * 64 + ((krow0 + u) ^ kwkey)) * 8];
            #pragma unroll
            for (int nt = 0; nt < 4; ++nt)
                accT[u][nt] = __builtin_amdgcn_mfma_f32_16x16x32_bf16(aw[nt], bf, accT[u][nt], 0, 0, 0);
        }
    }

    // ---- PV fully in-lane + store: out[p=c15][n] = sum_u att[u]*V[4p+u][n] + bv[n]
    #pragma unroll
    for (int nt = 0; nt < 4; ++nt) {
        const int h2 = nt >> 1;
        const ushort4 bv4 = *(const ushort4*)&bv[colbase + nt * 16 + qd * 4];
        const float bvf[4] = {bs2f(bv4.x), bs2f(bv4.y), bs2f(bv4.z), bs2f(bv4.w)};
        const int cbase = (b << 8) + colbase + nt * 16 + qd * 4;
        #pragma unroll
        for (int r = 0; r < 4; ++r) {
            float val = att[0][h2] * accT[0][nt][r];
            val += att[1][h2] * accT[1][nt][r];
            val += att[2][h2] * accT[2][nt][r];
            val += att[3][h2] * accT[3][nt][r];
            val += bvf[r];
            if (is_f32) {
                ((float*)out_raw)[(((size_t)(cbase + r)) << 16) + t0 + c15] = val;
            } else {
                ((u16*)out_raw)[(((size_t)(cbase + r)) << 16) + t0 + c15] = f2bs(val);
            }
        }
    }
}

extern "C" void kernel_launch(void* const* d_in, const int* in_sizes, int n_in,
                              void* d_out, int out_size, void* d_ws, size_t ws_size,
                              hipStream_t stream) {
    const size_t FEATT_BYTES = (size_t)1 << 26;   // 64 MB bf16 featT
    const size_t CANON_BYTES = (1u << 20) + (3u << 17) + 3 * 512;
    const int use_t = (ws_size >= FEATT_BYTES + CANON_BYTES) ? 1 : 0;   // ws_size constant -> capture-safe

    unsigned char* ws    = (unsigned char*)d_ws;
    unsigned char* canon = ws + (use_t ? FEATT_BYTES : 0);
    float* offsC = (float*)canon;
    u16* WqC = (u16*)(canon + (1u << 20));
    u16* WkC = (u16*)(canon + (1u << 20) + (1u << 17));
    u16* WvC = (u16*)(canon + (1u << 20) + (2u << 17));
    u16* bqC = (u16*)(canon + (1u << 20) + (3u << 17));
    u16* bkC = bqC + 256;
    u16* bvC = bkC + 256;

    irm_canon<<<1795, 256, 0, stream>>>(d_in[1], d_in[2], d_in[3], d_in[4],
                                        d_in[5], d_in[6], d_in[7], canon);
    if (use_t)
        irm_transpose<<<dim3(1024, 4, 2), 256, 0, stream>>>(d_in[0], (const u16*)d_in[1], (u16*)ws);
    irm_main<<<dim3(8192), 256, 0, stream>>>(use_t ? (const void*)ws : d_in[0], use_t,
                                             (const u16*)d_in[1], offsC,
                                             WqC, bqC, WkC, bkC, WvC, bvC, d_out);
}

// Round 5
// 624.533 us; speedup vs baseline: 2.3334x; 1.3503x over previous
//
#include <hip/hip_runtime.h>

// ImplicitResampleModule on MI355X (gfx950). Round: head-pair-chunked GEMMs.
// - Q/K/V GEMMs ALL operand-swapped (W as A-frag) -> Q, K rows, V rows, and
//   softmax for pixel p=c15 all in the SAME lane. Logits = in-lane FMAs +
//   shfl_xor over qd; PV = in-lane FMAs. NO LDS use after staging.
// - NEW: post-Q pipeline chunked by head-pair h2: {K-GEMM(2 nt) -> softmax ->
//   V-GEMM(2 nt, reusing accT) -> PV+store}. Accumulator peak 32 regs instead
//   of 64 -> kills the scratch spill that R3 (5.3GB) / R4 (1.7GB) suffered.
//   Each Wk/Wv column still loaded exactly once; only sFw LDS reads repeat.
// - sched_barrier(0) between phases: stop scheduler re-merging live ranges.
// - One barrier total. LDS = 40960 B. __launch_bounds__(256, 3).
//
// d_ws layout (use_t: ws >= 68,552,192 B):
//   [0, 64MB)            featT  u16 [B][HW][C]
//   [64MB, +1MB)         offsC  f32 [B*THW*2]
//   [+1MB, +128K ...)    WqC, WkC, WvC  u16[65536] each
//   [+1MB+384K, ...)     bqC, bkC, bvC  u16[256] each (512 B apart)

using short8 = __attribute__((ext_vector_type(8))) short;   // 8 bf16
using uint4v = __attribute__((ext_vector_type(4))) unsigned;
using f32x4  = __attribute__((ext_vector_type(4))) float;
typedef unsigned short u16;

#define LOG2_1E4 13.287712379549449f
#define TWO_PI   6.283185307179586f
#define ATT_SCL  0.17677669529663687f   // 32^-0.5

__device__ __forceinline__ float bs2f(u16 s) {
    unsigned u = ((unsigned)s) << 16;
    float f; __builtin_memcpy(&f, &u, 4); return f;
}
__device__ __forceinline__ u16 f2bs(float f) {
    unsigned u; __builtin_memcpy(&u, &f, 4);
    u += 0x7fffu + ((u >> 16) & 1u);   // RNE
    return (u16)(u >> 16);
}
// HW packed f32->bf16 (RNE): dst.lo = bf16(lo), dst.hi = bf16(hi)
__device__ __forceinline__ unsigned cvt_pk_bf16(float lo, float hi) {
    unsigned r;
    asm("v_cvt_pk_bf16_f32 %0, %1, %2" : "=v"(r) : "v"(lo), "v"(hi));
    return r;
}

// Probe: bf16-decode offs at even u16 indices. Block-uniform result.
__device__ __forceinline__ int probe_is_f32(const u16* offs_raw) {
    const int lane = threadIdx.x & 63;
    const float v = bs2f(offs_raw[lane * 2]);
    const float av = fabsf(v);
    const bool insane = !(av >= 1e-3f && av <= 1000.0f);   // NaN -> insane
    return __popcll(__ballot(insane)) >= 16 ? 1 : 0;
}

// ---------------- canonicalize offs / weights / biases ----------------
__global__ __launch_bounds__(256) void irm_canon(
    const void* offs_raw, const void* Wq_r, const void* bq_r,
    const void* Wk_r, const void* bk_r, const void* Wv_r, const void* bv_r,
    unsigned char* canon)
{
    const int is_f32 = probe_is_f32((const u16*)offs_raw);
    float* offsC = (float*)canon;
    u16* WqC = (u16*)(canon + (1u << 20));
    u16* WkC = (u16*)(canon + (1u << 20) + (1u << 17));
    u16* WvC = (u16*)(canon + (1u << 20) + (2u << 17));
    u16* bqC = (u16*)(canon + (1u << 20) + (3u << 17));
    u16* bkC = bqC + 256;
    u16* bvC = bkC + 256;

    const int gid = blockIdx.x * 256 + threadIdx.x;
    if (gid < 262144) {
        offsC[gid] = is_f32 ? ((const float*)offs_raw)[gid]
                            : bs2f(((const u16*)offs_raw)[gid]);
    } else if (gid < 262144 + 3 * 65536) {
        const int r = gid - 262144, w = r >> 16, i = r & 65535;
        const void* src = (w == 0) ? Wq_r : (w == 1) ? Wk_r : Wv_r;
        u16*       dst  = (w == 0) ? WqC  : (w == 1) ? WkC  : WvC;
        dst[i] = is_f32 ? f2bs(((const float*)src)[i]) : ((const u16*)src)[i];
    } else if (gid < 262144 + 3 * 65536 + 3 * 256) {
        const int r = gid - 262144 - 3 * 65536, w = r >> 8, i = r & 255;
        const void* src = (w == 0) ? bq_r : (w == 1) ? bk_r : bv_r;
        u16*       dst  = (w == 0) ? bqC  : (w == 1) ? bkC  : bvC;
        dst[i] = is_f32 ? f2bs(((const float*)src)[i]) : ((const u16*)src)[i];
    }
}

// ---------------- transpose feat [B,C,HW] -> featT bf16 [B,HW,C] ----------------
__global__ __launch_bounds__(256) void irm_transpose(const void* __restrict__ feat_raw,
                                                     const u16* __restrict__ offs_raw,
                                                     u16* __restrict__ featT) {
    const int is_f32 = probe_is_f32(offs_raw);
    __shared__ u16 tile[64][72];
    const int b   = blockIdx.z;
    const int c0  = blockIdx.y << 6;
    const int hw0 = blockIdx.x << 6;
    const int tid = threadIdx.x;
    const int r    = tid >> 4;          // 0..15
    const int col4 = (tid & 15) << 2;   // 0..60
    #pragma unroll
    for (int it = 0; it < 4; ++it) {
        const int c = (it << 4) + r;
        const size_t idx = ((size_t)((b << 8) + c0 + c) << 16) + hw0 + col4;
        ushort4 o;
        if (is_f32) {
            const float4 v = *(const float4*)((const float*)feat_raw + idx);
            const unsigned lo = cvt_pk_bf16(v.x, v.y);
            const unsigned hi = cvt_pk_bf16(v.z, v.w);
            o.x = (u16)(lo & 0xffffu); o.y = (u16)(lo >> 16);
            o.z = (u16)(hi & 0xffffu); o.w = (u16)(hi >> 16);
        } else {
            o = *(const ushort4*)((const u16*)feat_raw + idx);
        }
        *(ushort4*)&tile[c][col4 ^ (((c >> 3) & 7) << 3)] = o;
    }
    __syncthreads();
    const int s = tid & 7;    // c-octet
    const int m = tid >> 3;   // hw within half-tile
    #pragma unroll
    for (int it2 = 0; it2 < 2; ++it2) {
        const int hw = (it2 << 5) + m;
        short8 o;
        #pragma unroll
        for (int k = 0; k < 8; ++k) {
            const int c = (s << 3) + k;
            o[k] = (short)tile[c][hw ^ (((c >> 3) & 7) << 3)];
        }
        u16* dst = featT + (((size_t)((b << 16) + hw0 + hw)) << 8) + c0 + (s << 3);
        *(short8*)dst = o;
    }
}

// ---------------- main fused kernel ----------------
__global__ __launch_bounds__(256, 3) void irm_main(
    const void* __restrict__ fsrc,   // featT (bf16) if transposed else raw feat
    const int transposed,
    const u16* __restrict__ offs_raw,
    const float* __restrict__ offsC,
    const u16* __restrict__ Wq, const u16* __restrict__ bq,
    const u16* __restrict__ Wk, const u16* __restrict__ bk_unused,
    const u16* __restrict__ Wv, const u16* __restrict__ bv,
    void* __restrict__ out_raw)
{
    const int is_f32 = probe_is_f32(offs_raw);

    // LDS 40960 B.
    //  sFb [32 g][16 row][8 u16] @ 0      (8192 B)   row key = (g>>1)&7
    //  sFw [32 g][64 row][8 u16] @ 8192   (32768 B)  row key = (row>>3)&7
    __shared__ __align__(16) unsigned char smem[40960];
    u16* sFb = (u16*)smem;
    u16* sFw = (u16*)(smem + 8192);

    const int tid = threadIdx.x;
    const int raw = blockIdx.x;
    const int wq_ = ((raw & 7) << 10) | (raw >> 3);   // XCD swizzle (8192 % 8 == 0)
    const int b   = wq_ >> 12;
    const int t0  = (wq_ & 4095) << 4;

    const int p0 = tid >> 4;            // pixel 0..15
    const int cx = tid & 15;            // 16-channel group
    const int t  = t0 + p0;
    const float offx = offsC[((((size_t)b << 16) + (size_t)t) << 1) + 0];
    const float offy = offsC[((((size_t)b << 16) + (size_t)t) << 1) + 1];

    // ---- phase 0: gather + inline PE + stage fw, fb (k-sliced layouts) ----
    {
        const int ty = t >> 8, tx = t & 255;
        const float fy = (float)ty + offy;
        const float fx = (float)tx + offx;
        const float fiy = floorf(fy), fix = floorf(fx);
        const int iy = (int)fiy, ix = (int)fix;
        const float dy = fy - fiy, dx = fx - fix;

        int lin4[4];
        #pragma unroll
        for (int u = 0; u < 4; ++u) {
            int hy = iy + (u >> 1); hy = hy < 0 ? 0 : (hy > 255 ? 255 : hy);
            int wx = ix + (u & 1);  wx = wx < 0 ? 0 : (wx > 255 ? 255 : wx);
            lin4[u] = (hy << 8) | wx;
        }

        short8 g[4][2];
        if (transposed) {
            #pragma unroll
            for (int u = 0; u < 4; ++u) {
                const u16* src = (const u16*)fsrc +
                    ((((size_t)(b << 16)) + (size_t)lin4[u]) << 8) + (cx << 4);
                g[u][0] = *(const short8*)(src);
                g[u][1] = *(const short8*)(src + 8);
            }
        } else {
            #pragma unroll
            for (int u = 0; u < 4; ++u) {
                #pragma unroll
                for (int i = 0; i < 8; ++i) {
                    const size_t i0 = (((size_t)((b << 8) + (cx << 4) + i)) << 16) + lin4[u];
                    const size_t i1 = (((size_t)((b << 8) + (cx << 4) + 8 + i)) << 16) + lin4[u];
                    g[u][0][i] = is_f32 ? (short)f2bs(((const float*)fsrc)[i0]) : (short)((const u16*)fsrc)[i0];
                    g[u][1][i] = is_f32 ? (short)f2bs(((const float*)fsrc)[i1]) : (short)((const u16*)fsrc)[i1];
                }
            }
        }

        // inline PE: channel pair a covers c = 16cx + 2a, 2a+1; j = (8cx+a)&63
        float invt[8], s1[8], c1[8];
        #pragma unroll
        for (int a = 0; a < 8; ++a) {
            const int j = ((cx << 3) + a) & 63;
            invt[a] = exp2f(-(float)j * (LOG2_1E4 / 64.0f));
            const float arg = (TWO_PI / (1.0f + 1e-6f)) * invt[a];
            __sincosf(arg, &s1[a], &c1[a]);
        }

        const bool hi_half = (cx >= 8);   // c >= 128 -> x half
        float gsum[16];
        #pragma unroll
        for (int i = 0; i < 16; ++i) gsum[i] = 0.0f;

        #pragma unroll
        for (int u = 0; u < 4; ++u) {
            const bool sel = hi_half ? (bool)(u & 1) : (bool)(u >> 1);
            unsigned pk[8];
            #pragma unroll
            for (int a = 0; a < 8; ++a) {
                const float f0 = bs2f((u16)g[u][a >> 2][(2 * a) & 7]);
                const float f1 = bs2f((u16)g[u][a >> 2][(2 * a + 1) & 7]);
                gsum[2 * a]     += f0;
                gsum[2 * a + 1] += f1;
                const float w0 = f0 + (sel ? s1[a] : 0.0f);
                const float w1 = f1 + (sel ? c1[a] : 1.0f);
                pk[a] = cvt_pk_bf16(w0, w1);
            }
            const int row = (p0 << 2) + u;
            const int rp  = row ^ ((row >> 3) & 7);
            const uint4v lo = {pk[0], pk[1], pk[2], pk[3]};
            const uint4v hi = {pk[4], pk[5], pk[6], pk[7]};
            *(uint4v*)&sFw[(((2 * cx) * 64 + rp)) * 8]     = lo;
            *(uint4v*)&sFw[(((2 * cx + 1) * 64 + rp)) * 8] = hi;
        }

        // fb = mean_u + PE(deci, card = 2)
        const float ys = dy * (TWO_PI / (2.0f + 1e-6f));
        const float xs = dx * (TWO_PI / (2.0f + 1e-6f));
        const float sxy = hi_half ? xs : ys;
        unsigned qk[8];
        #pragma unroll
        for (int a = 0; a < 8; ++a) {
            float s2, c2;
            __sincosf(sxy * invt[a], &s2, &c2);
            qk[a] = cvt_pk_bf16(gsum[2 * a] * 0.25f + s2, gsum[2 * a + 1] * 0.25f + c2);
        }
        const int rb = p0 ^ (cx & 7);
        const uint4v qlo = {qk[0], qk[1], qk[2], qk[3]};
        const uint4v qhi = {qk[4], qk[5], qk[6], qk[7]};
        *(uint4v*)&sFb[((2 * cx) * 16 + rb) * 8]     = qlo;
        *(uint4v*)&sFb[((2 * cx + 1) * 16 + rb) * 8] = qhi;
    }
    __syncthreads();   // the only barrier: all LDS RAW pairs cross it

    const int lane = tid & 63;
    const int wv   = tid >> 6;
    const int c15  = lane & 15;
    const int qd   = lane >> 4;
    const int colbase = wv << 6;
    const f32x4 zero4 = {0.f, 0.f, 0.f, 0.f};
    const int kwkey = (c15 >> 1) & 7;    // = ((4*c15+u)>>3)&7 for u in 0..3
    const int krow0 = 4 * c15;

    // ---- Q^T GEMM (swapped): accQt[nt][r] = Q[p=c15][colbase+16nt+4qd+r] (+bq)
    f32x4 accQt[4];
    #pragma unroll
    for (int nt = 0; nt < 4; ++nt) accQt[nt] = zero4;
    #pragma unroll
    for (int ks = 0; ks < 8; ++ks) {
        const int gidx = ks * 4 + qd;
        const short8 bfb = *(const short8*)&sFb[(gidx * 16 + (c15 ^ ((gidx >> 1) & 7))) * 8];
        #pragma unroll
        for (int nt = 0; nt < 4; ++nt) {
            const short8 aw = *(const short8*)&Wq[(colbase + nt * 16 + c15) * 256 + ks * 32 + qd * 8];
            accQt[nt] = __builtin_amdgcn_mfma_f32_16x16x32_bf16(aw, bfb, accQt[nt], 0, 0, 0);
        }
    }
    #pragma unroll
    for (int nt = 0; nt < 4; ++nt) {
        const ushort4 b4 = *(const ushort4*)&bq[colbase + nt * 16 + qd * 4];
        accQt[nt][0] += bs2f(b4.x); accQt[nt][1] += bs2f(b4.y);
        accQt[nt][2] += bs2f(b4.z); accQt[nt][3] += bs2f(b4.w);
    }
    __builtin_amdgcn_sched_barrier(0);

    // ---- per-head-pair pipeline: K-GEMM -> softmax -> V-GEMM -> PV+store ----
    // accT[4 u][2 ntl] = 32 f32 regs, reused K-phase then V-phase, per h2.
    #pragma unroll
    for (int h2 = 0; h2 < 2; ++h2) {
        // K chunk: accT[u][ntl][r] = K[4c15+u][colbase+16(2h2+ntl)+4qd+r]
        //          (bk is u-independent per (p,h) -> cancels in softmax; dropped)
        f32x4 accT[4][2];
        #pragma unroll
        for (int u = 0; u < 4; ++u)
            #pragma unroll
            for (int ntl = 0; ntl < 2; ++ntl) accT[u][ntl] = zero4;
        #pragma unroll
        for (int ks = 0; ks < 8; ++ks) {
            short8 aw[2];
            #pragma unroll
            for (int ntl = 0; ntl < 2; ++ntl)
                aw[ntl] = *(const short8*)&Wk[(colbase + (2 * h2 + ntl) * 16 + c15) * 256 + ks * 32 + qd * 8];
            #pragma unroll
            for (int u = 0; u < 4; ++u) {
                const short8 bf = *(const short8*)&sFw[((ks * 4 + qd) * 64 + ((krow0 + u) ^ kwkey)) * 8];
                #pragma unroll
                for (int ntl = 0; ntl < 2; ++ntl)
                    accT[u][ntl] = __builtin_amdgcn_mfma_f32_16x16x32_bf16(aw[ntl], bf, accT[u][ntl], 0, 0, 0);
            }
        }

        // logits for head h = 2wv + h2 (pixel p = c15), reduce over qd; f32 softmax
        float att[4];
        {
            float lg[4];
            #pragma unroll
            for (int u = 0; u < 4; ++u) {
                float acc = 0.0f;
                #pragma unroll
                for (int ntl = 0; ntl < 2; ++ntl)
                    #pragma unroll
                    for (int r = 0; r < 4; ++r)
                        acc += accQt[2 * h2 + ntl][r] * accT[u][ntl][r];
                acc += __shfl_xor(acc, 16);
                acc += __shfl_xor(acc, 32);
                lg[u] = acc * ATT_SCL;
            }
            const float mx = fmaxf(fmaxf(lg[0], lg[1]), fmaxf(lg[2], lg[3]));
            float e[4], es = 0.0f;
            #pragma unroll
            for (int u = 0; u < 4; ++u) { e[u] = __expf(lg[u] - mx); es += e[u]; }
            const float inv = __fdividef(1.0f, es);
            #pragma unroll
            for (int u = 0; u < 4; ++u) att[u] = e[u] * inv;
        }
        __builtin_amdgcn_sched_barrier(0);

        // V chunk (reuse accT): accT[u][ntl][r] = V[4c15+u][colbase+16(2h2+ntl)+4qd+r]
        #pragma unroll
        for (int u = 0; u < 4; ++u)
            #pragma unroll
            for (int ntl = 0; ntl < 2; ++ntl) accT[u][ntl] = zero4;
        #pragma unroll
        for (int ks = 0; ks < 8; ++ks) {
            short8 aw[2];
            #pragma unroll
            for (int ntl = 0; ntl < 2; ++ntl)
                aw[ntl] = *(const short8*)&Wv[(colbase + (2 * h2 + ntl) * 16 + c15) * 256 + ks * 32 + qd * 8];
            #pragma unroll
            for (int u = 0; u < 4; ++u) {
                const short8 bf = *(const short8*)&sFw[((ks * 4 + qd) * 64 + ((krow0 + u) ^ kwkey)) * 8];
                #pragma unroll
                for (int ntl = 0; ntl < 2; ++ntl)
                    accT[u][ntl] = __builtin_amdgcn_mfma_f32_16x16x32_bf16(aw[ntl], bf, accT[u][ntl], 0, 0, 0);
            }
        }

        // PV fully in-lane + store: out[p=c15][n] = sum_u att[u]*V[4p+u][n] + bv[n]
        #pragma unroll
        for (int ntl = 0; ntl < 2; ++ntl) {
            const int nt = 2 * h2 + ntl;
            const ushort4 bv4 = *(const ushort4*)&bv[colbase + nt * 16 + qd * 4];
            const float bvf[4] = {bs2f(bv4.x), bs2f(bv4.y), bs2f(bv4.z), bs2f(bv4.w)};
            const int cbase = (b << 8) + colbase + nt * 16 + qd * 4;
            #pragma unroll
            for (int r = 0; r < 4; ++r) {
                float val = att[0] * accT[0][ntl][r];
                val += att[1] * accT[1][ntl][r];
                val += att[2] * accT[2][ntl][r];
                val += att[3] * accT[3][ntl][r];
                val += bvf[r];
                if (is_f32) {
                    ((float*)out_raw)[(((size_t)(cbase + r)) << 16) + t0 + c15] = val;
                } else {
                    ((u16*)out_raw)[(((size_t)(cbase + r)) << 16) + t0 + c15] = f2bs(val);
                }
            }
        }
        __builtin_amdgcn_sched_barrier(0);
    }
}

extern "C" void kernel_launch(void* const* d_in, const int* in_sizes, int n_in,
                              void* d_out, int out_size, void* d_ws, size_t ws_size,
                              hipStream_t stream) {
    const size_t FEATT_BYTES = (size_t)1 << 26;   // 64 MB bf16 featT
    const size_t CANON_BYTES = (1u << 20) + (3u << 17) + 3 * 512;
    const int use_t = (ws_size >= FEATT_BYTES + CANON_BYTES) ? 1 : 0;   // ws_size constant -> capture-safe

    unsigned char* ws    = (unsigned char*)d_ws;
    unsigned char* canon = ws + (use_t ? FEATT_BYTES : 0);
    float* offsC = (float*)canon;
    u16* WqC = (u16*)(canon + (1u << 20));
    u16* WkC = (u16*)(canon + (1u << 20) + (1u << 17));
    u16* WvC = (u16*)(canon + (1u << 20) + (2u << 17));
    u16* bqC = (u16*)(canon + (1u << 20) + (3u << 17));
    u16* bkC = bqC + 256;
    u16* bvC = bkC + 256;

    irm_canon<<<1795, 256, 0, stream>>>(d_in[1], d_in[2], d_in[3], d_in[4],
                                        d_in[5], d_in[6], d_in[7], canon);
    if (use_t)
        irm_transpose<<<dim3(1024, 4, 2), 256, 0, stream>>>(d_in[0], (const u16*)d_in[1], (u16*)ws);
    irm_main<<<dim3(8192), 256, 0, stream>>>(use_t ? (const void*)ws : d_in[0], use_t,
                                             (const u16*)d_in[1], offsC,
                                             WqC, bqC, WkC, bkC, WvC, bvC, d_out);
}

// Round 6
// 611.953 us; speedup vs baseline: 2.3813x; 1.0206x over previous
//
#include <hip/hip_runtime.h>

// ImplicitResampleModule on MI355X (gfx950). Round: occupancy bid (256,4).
// - Identical structure to R5 (head-pair-chunked, all-swapped MFMA, 1 barrier,
//   LDS 40960 B). R5 counters: no spill (FETCH 36MB/WRITE 131MB), VGPR=68,
//   dur 420us at 33.8% occ == R1's 424 at same occ with a very different
//   structure -> latency-stall-bound; the working lever is occupancy.
// - ONLY change: __launch_bounds__(256, 4). Budget 128 unified regs/wave;
//   static peak ~116 (68 arch + 48 acc) now fits (R3's 150-reg version did
//   not -> that spill is what the h2-chunking fixed).
// - LDS 40960 B = 160K/4 exactly -> 4 blocks/CU, 16 waves/CU (50% occ cap).
// - A/B check for this round: FETCH/WRITE stay at 36/131 MB -> no spill.
//
// d_ws layout (use_t: ws >= 68,552,192 B):
//   [0, 64MB)            featT  u16 [B][HW][C]
//   [64MB, +1MB)         offsC  f32 [B*THW*2]
//   [+1MB, +128K ...)    WqC, WkC, WvC  u16[65536] each
//   [+1MB+384K, ...)     bqC, bkC, bvC  u16[256] each (512 B apart)

using short8 = __attribute__((ext_vector_type(8))) short;   // 8 bf16
using uint4v = __attribute__((ext_vector_type(4))) unsigned;
using f32x4  = __attribute__((ext_vector_type(4))) float;
typedef unsigned short u16;

#define LOG2_1E4 13.287712379549449f
#define TWO_PI   6.283185307179586f
#define ATT_SCL  0.17677669529663687f   // 32^-0.5

__device__ __forceinline__ float bs2f(u16 s) {
    unsigned u = ((unsigned)s) << 16;
    float f; __builtin_memcpy(&f, &u, 4); return f;
}
__device__ __forceinline__ u16 f2bs(float f) {
    unsigned u; __builtin_memcpy(&u, &f, 4);
    u += 0x7fffu + ((u >> 16) & 1u);   // RNE
    return (u16)(u >> 16);
}
// HW packed f32->bf16 (RNE): dst.lo = bf16(lo), dst.hi = bf16(hi)
__device__ __forceinline__ unsigned cvt_pk_bf16(float lo, float hi) {
    unsigned r;
    asm("v_cvt_pk_bf16_f32 %0, %1, %2" : "=v"(r) : "v"(lo), "v"(hi));
    return r;
}

// Probe: bf16-decode offs at even u16 indices. Block-uniform result.
__device__ __forceinline__ int probe_is_f32(const u16* offs_raw) {
    const int lane = threadIdx.x & 63;
    const float v = bs2f(offs_raw[lane * 2]);
    const float av = fabsf(v);
    const bool insane = !(av >= 1e-3f && av <= 1000.0f);   // NaN -> insane
    return __popcll(__ballot(insane)) >= 16 ? 1 : 0;
}

// ---------------- canonicalize offs / weights / biases ----------------
__global__ __launch_bounds__(256) void irm_canon(
    const void* offs_raw, const void* Wq_r, const void* bq_r,
    const void* Wk_r, const void* bk_r, const void* Wv_r, const void* bv_r,
    unsigned char* canon)
{
    const int is_f32 = probe_is_f32((const u16*)offs_raw);
    float* offsC = (float*)canon;
    u16* WqC = (u16*)(canon + (1u << 20));
    u16* WkC = (u16*)(canon + (1u << 20) + (1u << 17));
    u16* WvC = (u16*)(canon + (1u << 20) + (2u << 17));
    u16* bqC = (u16*)(canon + (1u << 20) + (3u << 17));
    u16* bkC = bqC + 256;
    u16* bvC = bkC + 256;

    const int gid = blockIdx.x * 256 + threadIdx.x;
    if (gid < 262144) {
        offsC[gid] = is_f32 ? ((const float*)offs_raw)[gid]
                            : bs2f(((const u16*)offs_raw)[gid]);
    } else if (gid < 262144 + 3 * 65536) {
        const int r = gid - 262144, w = r >> 16, i = r & 65535;
        const void* src = (w == 0) ? Wq_r : (w == 1) ? Wk_r : Wv_r;
        u16*       dst  = (w == 0) ? WqC  : (w == 1) ? WkC  : WvC;
        dst[i] = is_f32 ? f2bs(((const float*)src)[i]) : ((const u16*)src)[i];
    } else if (gid < 262144 + 3 * 65536 + 3 * 256) {
        const int r = gid - 262144 - 3 * 65536, w = r >> 8, i = r & 255;
        const void* src = (w == 0) ? bq_r : (w == 1) ? bk_r : bv_r;
        u16*       dst  = (w == 0) ? bqC  : (w == 1) ? bkC  : bvC;
        dst[i] = is_f32 ? f2bs(((const float*)src)[i]) : ((const u16*)src)[i];
    }
}

// ---------------- transpose feat [B,C,HW] -> featT bf16 [B,HW,C] ----------------
__global__ __launch_bounds__(256) void irm_transpose(const void* __restrict__ feat_raw,
                                                     const u16* __restrict__ offs_raw,
                                                     u16* __restrict__ featT) {
    const int is_f32 = probe_is_f32(offs_raw);
    __shared__ u16 tile[64][72];
    const int b   = blockIdx.z;
    const int c0  = blockIdx.y << 6;
    const int hw0 = blockIdx.x << 6;
    const int tid = threadIdx.x;
    const int r    = tid >> 4;          // 0..15
    const int col4 = (tid & 15) << 2;   // 0..60
    #pragma unroll
    for (int it = 0; it < 4; ++it) {
        const int c = (it << 4) + r;
        const size_t idx = ((size_t)((b << 8) + c0 + c) << 16) + hw0 + col4;
        ushort4 o;
        if (is_f32) {
            const float4 v = *(const float4*)((const float*)feat_raw + idx);
            const unsigned lo = cvt_pk_bf16(v.x, v.y);
            const unsigned hi = cvt_pk_bf16(v.z, v.w);
            o.x = (u16)(lo & 0xffffu); o.y = (u16)(lo >> 16);
            o.z = (u16)(hi & 0xffffu); o.w = (u16)(hi >> 16);
        } else {
            o = *(const ushort4*)((const u16*)feat_raw + idx);
        }
        *(ushort4*)&tile[c][col4 ^ (((c >> 3) & 7) << 3)] = o;
    }
    __syncthreads();
    const int s = tid & 7;    // c-octet
    const int m = tid >> 3;   // hw within half-tile
    #pragma unroll
    for (int it2 = 0; it2 < 2; ++it2) {
        const int hw = (it2 << 5) + m;
        short8 o;
        #pragma unroll
        for (int k = 0; k < 8; ++k) {
            const int c = (s << 3) + k;
            o[k] = (short)tile[c][hw ^ (((c >> 3) & 7) << 3)];
        }
        u16* dst = featT + (((size_t)((b << 16) + hw0 + hw)) << 8) + c0 + (s << 3);
        *(short8*)dst = o;
    }
}

// ---------------- main fused kernel ----------------
__global__ __launch_bounds__(256, 4) void irm_main(
    const void* __restrict__ fsrc,   // featT (bf16) if transposed else raw feat
    const int transposed,
    const u16* __restrict__ offs_raw,
    const float* __restrict__ offsC,
    const u16* __restrict__ Wq, const u16* __restrict__ bq,
    const u16* __restrict__ Wk, const u16* __restrict__ bk_unused,
    const u16* __restrict__ Wv, const u16* __restrict__ bv,
    void* __restrict__ out_raw)
{
    const int is_f32 = probe_is_f32(offs_raw);

    // LDS 40960 B -> 4 blocks/CU.
    //  sFb [32 g][16 row][8 u16] @ 0      (8192 B)   row key = (g>>1)&7
    //  sFw [32 g][64 row][8 u16] @ 8192   (32768 B)  row key = (row>>3)&7
    __shared__ __align__(16) unsigned char smem[40960];
    u16* sFb = (u16*)smem;
    u16* sFw = (u16*)(smem + 8192);

    const int tid = threadIdx.x;
    const int raw = blockIdx.x;
    const int wq_ = ((raw & 7) << 10) | (raw >> 3);   // XCD swizzle (8192 % 8 == 0)
    const int b   = wq_ >> 12;
    const int t0  = (wq_ & 4095) << 4;

    const int p0 = tid >> 4;            // pixel 0..15
    const int cx = tid & 15;            // 16-channel group
    const int t  = t0 + p0;
    const float offx = offsC[((((size_t)b << 16) + (size_t)t) << 1) + 0];
    const float offy = offsC[((((size_t)b << 16) + (size_t)t) << 1) + 1];

    // ---- phase 0: gather + inline PE + stage fw, fb (k-sliced layouts) ----
    {
        const int ty = t >> 8, tx = t & 255;
        const float fy = (float)ty + offy;
        const float fx = (float)tx + offx;
        const float fiy = floorf(fy), fix = floorf(fx);
        const int iy = (int)fiy, ix = (int)fix;
        const float dy = fy - fiy, dx = fx - fix;

        int lin4[4];
        #pragma unroll
        for (int u = 0; u < 4; ++u) {
            int hy = iy + (u >> 1); hy = hy < 0 ? 0 : (hy > 255 ? 255 : hy);
            int wx = ix + (u & 1);  wx = wx < 0 ? 0 : (wx > 255 ? 255 : wx);
            lin4[u] = (hy << 8) | wx;
        }

        short8 g[4][2];
        if (transposed) {
            #pragma unroll
            for (int u = 0; u < 4; ++u) {
                const u16* src = (const u16*)fsrc +
                    ((((size_t)(b << 16)) + (size_t)lin4[u]) << 8) + (cx << 4);
                g[u][0] = *(const short8*)(src);
                g[u][1] = *(const short8*)(src + 8);
            }
        } else {
            #pragma unroll
            for (int u = 0; u < 4; ++u) {
                #pragma unroll
                for (int i = 0; i < 8; ++i) {
                    const size_t i0 = (((size_t)((b << 8) + (cx << 4) + i)) << 16) + lin4[u];
                    const size_t i1 = (((size_t)((b << 8) + (cx << 4) + 8 + i)) << 16) + lin4[u];
                    g[u][0][i] = is_f32 ? (short)f2bs(((const float*)fsrc)[i0]) : (short)((const u16*)fsrc)[i0];
                    g[u][1][i] = is_f32 ? (short)f2bs(((const float*)fsrc)[i1]) : (short)((const u16*)fsrc)[i1];
                }
            }
        }

        // inline PE: channel pair a covers c = 16cx + 2a, 2a+1; j = (8cx+a)&63
        float invt[8], s1[8], c1[8];
        #pragma unroll
        for (int a = 0; a < 8; ++a) {
            const int j = ((cx << 3) + a) & 63;
            invt[a] = exp2f(-(float)j * (LOG2_1E4 / 64.0f));
            const float arg = (TWO_PI / (1.0f + 1e-6f)) * invt[a];
            __sincosf(arg, &s1[a], &c1[a]);
        }

        const bool hi_half = (cx >= 8);   // c >= 128 -> x half
        float gsum[16];
        #pragma unroll
        for (int i = 0; i < 16; ++i) gsum[i] = 0.0f;

        #pragma unroll
        for (int u = 0; u < 4; ++u) {
            const bool sel = hi_half ? (bool)(u & 1) : (bool)(u >> 1);
            unsigned pk[8];
            #pragma unroll
            for (int a = 0; a < 8; ++a) {
                const float f0 = bs2f((u16)g[u][a >> 2][(2 * a) & 7]);
                const float f1 = bs2f((u16)g[u][a >> 2][(2 * a + 1) & 7]);
                gsum[2 * a]     += f0;
                gsum[2 * a + 1] += f1;
                const float w0 = f0 + (sel ? s1[a] : 0.0f);
                const float w1 = f1 + (sel ? c1[a] : 1.0f);
                pk[a] = cvt_pk_bf16(w0, w1);
            }
            const int row = (p0 << 2) + u;
            const int rp  = row ^ ((row >> 3) & 7);
            const uint4v lo = {pk[0], pk[1], pk[2], pk[3]};
            const uint4v hi = {pk[4], pk[5], pk[6], pk[7]};
            *(uint4v*)&sFw[(((2 * cx) * 64 + rp)) * 8]     = lo;
            *(uint4v*)&sFw[(((2 * cx + 1) * 64 + rp)) * 8] = hi;
        }

        // fb = mean_u + PE(deci, card = 2)
        const float ys = dy * (TWO_PI / (2.0f + 1e-6f));
        const float xs = dx * (TWO_PI / (2.0f + 1e-6f));
        const float sxy = hi_half ? xs : ys;
        unsigned qk[8];
        #pragma unroll
        for (int a = 0; a < 8; ++a) {
            float s2, c2;
            __sincosf(sxy * invt[a], &s2, &c2);
            qk[a] = cvt_pk_bf16(gsum[2 * a] * 0.25f + s2, gsum[2 * a + 1] * 0.25f + c2);
        }
        const int rb = p0 ^ (cx & 7);
        const uint4v qlo = {qk[0], qk[1], qk[2], qk[3]};
        const uint4v qhi = {qk[4], qk[5], qk[6], qk[7]};
        *(uint4v*)&sFb[((2 * cx) * 16 + rb) * 8]     = qlo;
        *(uint4v*)&sFb[((2 * cx + 1) * 16 + rb) * 8] = qhi;
    }
    __syncthreads();   // the only barrier: all LDS RAW pairs cross it

    const int lane = tid & 63;
    const int wv   = tid >> 6;
    const int c15  = lane & 15;
    const int qd   = lane >> 4;
    const int colbase = wv << 6;
    const f32x4 zero4 = {0.f, 0.f, 0.f, 0.f};
    const int kwkey = (c15 >> 1) & 7;    // = ((4*c15+u)>>3)&7 for u in 0..3
    const int krow0 = 4 * c15;

    // ---- Q^T GEMM (swapped): accQt[nt][r] = Q[p=c15][colbase+16nt+4qd+r] (+bq)
    f32x4 accQt[4];
    #pragma unroll
    for (int nt = 0; nt < 4; ++nt) accQt[nt] = zero4;
    #pragma unroll
    for (int ks = 0; ks < 8; ++ks) {
        const int gidx = ks * 4 + qd;
        const short8 bfb = *(const short8*)&sFb[(gidx * 16 + (c15 ^ ((gidx >> 1) & 7))) * 8];
        #pragma unroll
        for (int nt = 0; nt < 4; ++nt) {
            const short8 aw = *(const short8*)&Wq[(colbase + nt * 16 + c15) * 256 + ks * 32 + qd * 8];
            accQt[nt] = __builtin_amdgcn_mfma_f32_16x16x32_bf16(aw, bfb, accQt[nt], 0, 0, 0);
        }
    }
    #pragma unroll
    for (int nt = 0; nt < 4; ++nt) {
        const ushort4 b4 = *(const ushort4*)&bq[colbase + nt * 16 + qd * 4];
        accQt[nt][0] += bs2f(b4.x); accQt[nt][1] += bs2f(b4.y);
        accQt[nt][2] += bs2f(b4.z); accQt[nt][3] += bs2f(b4.w);
    }
    __builtin_amdgcn_sched_barrier(0);

    // ---- per-head-pair pipeline: K-GEMM -> softmax -> V-GEMM -> PV+store ----
    // accT[4 u][2 ntl] = 32 f32 regs, reused K-phase then V-phase, per h2.
    #pragma unroll
    for (int h2 = 0; h2 < 2; ++h2) {
        // K chunk: accT[u][ntl][r] = K[4c15+u][colbase+16(2h2+ntl)+4qd+r]
        //          (bk is u-independent per (p,h) -> cancels in softmax; dropped)
        f32x4 accT[4][2];
        #pragma unroll
        for (int u = 0; u < 4; ++u)
            #pragma unroll
            for (int ntl = 0; ntl < 2; ++ntl) accT[u][ntl] = zero4;
        #pragma unroll
        for (int ks = 0; ks < 8; ++ks) {
            short8 aw[2];
            #pragma unroll
            for (int ntl = 0; ntl < 2; ++ntl)
                aw[ntl] = *(const short8*)&Wk[(colbase + (2 * h2 + ntl) * 16 + c15) * 256 + ks * 32 + qd * 8];
            #pragma unroll
            for (int u = 0; u < 4; ++u) {
                const short8 bf = *(const short8*)&sFw[((ks * 4 + qd) * 64 + ((krow0 + u) ^ kwkey)) * 8];
                #pragma unroll
                for (int ntl = 0; ntl < 2; ++ntl)
                    accT[u][ntl] = __builtin_amdgcn_mfma_f32_16x16x32_bf16(aw[ntl], bf, accT[u][ntl], 0, 0, 0);
            }
        }

        // logits for head h = 2wv + h2 (pixel p = c15), reduce over qd; f32 softmax
        float att[4];
        {
            float lg[4];
            #pragma unroll
            for (int u = 0; u < 4; ++u) {
                float acc = 0.0f;
                #pragma unroll
                for (int ntl = 0; ntl < 2; ++ntl)
                    #pragma unroll
                    for (int r = 0; r < 4; ++r)
                        acc += accQt[2 * h2 + ntl][r] * accT[u][ntl][r];
                acc += __shfl_xor(acc, 16);
                acc += __shfl_xor(acc, 32);
                lg[u] = acc * ATT_SCL;
            }
            const float mx = fmaxf(fmaxf(lg[0], lg[1]), fmaxf(lg[2], lg[3]));
            float e[4], es = 0.0f;
            #pragma unroll
            for (int u = 0; u < 4; ++u) { e[u] = __expf(lg[u] - mx); es += e[u]; }
            const float inv = __fdividef(1.0f, es);
            #pragma unroll
            for (int u = 0; u < 4; ++u) att[u] = e[u] * inv;
        }
        __builtin_amdgcn_sched_barrier(0);

        // V chunk (reuse accT): accT[u][ntl][r] = V[4c15+u][colbase+16(2h2+ntl)+4qd+r]
        #pragma unroll
        for (int u = 0; u < 4; ++u)
            #pragma unroll
            for (int ntl = 0; ntl < 2; ++ntl) accT[u][ntl] = zero4;
        #pragma unroll
        for (int ks = 0; ks < 8; ++ks) {
            short8 aw[2];
            #pragma unroll
            for (int ntl = 0; ntl < 2; ++ntl)
                aw[ntl] = *(const short8*)&Wv[(colbase + (2 * h2 + ntl) * 16 + c15) * 256 + ks * 32 + qd * 8];
            #pragma unroll
            for (int u = 0; u < 4; ++u) {
                const short8 bf = *(const short8*)&sFw[((ks * 4 + qd) * 64 + ((krow0 + u) ^ kwkey)) * 8];
                #pragma unroll
                for (int ntl = 0; ntl < 2; ++ntl)
                    accT[u][ntl] = __builtin_amdgcn_mfma_f32_16x16x32_bf16(aw[ntl], bf, accT[u][ntl], 0, 0, 0);
            }
        }

        // PV fully in-lane + store: out[p=c15][n] = sum_u att[u]*V[4p+u][n] + bv[n]
        #pragma unroll
        for (int ntl = 0; ntl < 2; ++ntl) {
            const int nt = 2 * h2 + ntl;
            const ushort4 bv4 = *(const ushort4*)&bv[colbase + nt * 16 + qd * 4];
            const float bvf[4] = {bs2f(bv4.x), bs2f(bv4.y), bs2f(bv4.z), bs2f(bv4.w)};
            const int cbase = (b << 8) + colbase + nt * 16 + qd * 4;
            #pragma unroll
            for (int r = 0; r < 4; ++r) {
                float val = att[0] * accT[0][ntl][r];
                val += att[1] * accT[1][ntl][r];
                val += att[2] * accT[2][ntl][r];
                val += att[3] * accT[3][ntl][r];
                val += bvf[r];
                if (is_f32) {
                    ((float*)out_raw)[(((size_t)(cbase + r)) << 16) + t0 + c15] = val;
                } else {
                    ((u16*)out_raw)[(((size_t)(cbase + r)) << 16) + t0 + c15] = f2bs(val);
                }
            }
        }
        __builtin_amdgcn_sched_barrier(0);
    }
}

extern "C" void kernel_launch(void* const* d_in, const int* in_sizes, int n_in,
                              void* d_out, int out_size, void* d_ws, size_t ws_size,
                              hipStream_t stream) {
    const size_t FEATT_BYTES = (size_t)1 << 26;   // 64 MB bf16 featT
    const size_t CANON_BYTES = (1u << 20) + (3u << 17) + 3 * 512;
    const int use_t = (ws_size >= FEATT_BYTES + CANON_BYTES) ? 1 : 0;   // ws_size constant -> capture-safe

    unsigned char* ws    = (unsigned char*)d_ws;
    unsigned char* canon = ws + (use_t ? FEATT_BYTES : 0);
    float* offsC = (float*)canon;
    u16* WqC = (u16*)(canon + (1u << 20));
    u16* WkC = (u16*)(canon + (1u << 20) + (1u << 17));
    u16* WvC = (u16*)(canon + (1u << 20) + (2u << 17));
    u16* bqC = (u16*)(canon + (1u << 20) + (3u << 17));
    u16* bkC = bqC + 256;
    u16* bvC = bkC + 256;

    irm_canon<<<1795, 256, 0, stream>>>(d_in[1], d_in[2], d_in[3], d_in[4],
                                        d_in[5], d_in[6], d_in[7], canon);
    if (use_t)
        irm_transpose<<<dim3(1024, 4, 2), 256, 0, stream>>>(d_in[0], (const u16*)d_in[1], (u16*)ws);
    irm_main<<<dim3(8192), 256, 0, stream>>>(use_t ? (const void*)ws : d_in[0], use_t,
                                             (const u16*)d_in[1], offsC,
                                             WqC, bqC, WkC, bkC, WvC, bvC, d_out);
}